// Round 3
// baseline (310.689 us; speedup 1.0000x reference)
//
#include <hip/hip_runtime.h>
#include <hip/hip_bf16.h>
#include <stdint.h>

typedef __hip_bfloat16 bf16;
typedef __attribute__((ext_vector_type(8))) short bf16x8;
typedef __attribute__((ext_vector_type(4))) float f32x4;

#define MFMA16(a,b,c) __builtin_amdgcn_mfma_f32_16x16x32_bf16((a),(b),(c),0,0,0)

#define B_ 2
#define T_ 2048
#define E_ 1024
#define H_ 16
#define D_ 64
#define M_ (B_*T_)   // 4096
#define PROJ_ELEMS (32ull * 2048ull * 64ull)   // 4.19M elems per Q/K/V tensor

__device__ __forceinline__ void gload_lds16(const bf16* g, bf16* l) {
  __builtin_amdgcn_global_load_lds(
      (const __attribute__((address_space(1))) unsigned int*)g,
      (__attribute__((address_space(3))) unsigned int*)l,
      16, 0, 0);
}

// ---------------- pre-pass: f32 -> bf16 convert ----------------
__global__ __launch_bounds__(256) void cvt_x_kernel(const float* __restrict__ in,
                                                    bf16* __restrict__ out) {
  int i = blockIdx.x * 256 + threadIdx.x;        // each thread: 4 floats
  float4 v = reinterpret_cast<const float4*>(in)[i];
  union { bf16 h[4]; unsigned long long u; } t;
  t.h[0] = __float2bfloat16(v.x);
  t.h[1] = __float2bfloat16(v.y);
  t.h[2] = __float2bfloat16(v.z);
  t.h[3] = __float2bfloat16(v.w);
  reinterpret_cast<unsigned long long*>(out)[i] = t.u;
}

// ---------------- pre-pass: 4x W [K][N] f32 -> Wt [N][K] bf16 (fused) ----------------
__global__ __launch_bounds__(256) void transpose_cvt4_kernel(
    const float* __restrict__ W0, const float* __restrict__ W1,
    const float* __restrict__ W2, const float* __restrict__ W3,
    bf16* __restrict__ T0, bf16* __restrict__ T1,
    bf16* __restrict__ T2, bf16* __restrict__ T3) {
  __shared__ float tile[32][33];
  const float* W; bf16* Wt;
  switch (blockIdx.z) {
    case 0: W = W0; Wt = T0; break;
    case 1: W = W1; Wt = T1; break;
    case 2: W = W2; Wt = T2; break;
    default: W = W3; Wt = T3; break;
  }
  const int tx = threadIdx.x, ty = threadIdx.y;  // 32 x 8
  const int n0 = blockIdx.x * 32, k0 = blockIdx.y * 32;
#pragma unroll
  for (int i = 0; i < 4; i++)
    tile[ty + 8*i][tx] = W[(size_t)(k0 + ty + 8*i) * E_ + n0 + tx];
  __syncthreads();
#pragma unroll
  for (int i = 0; i < 4; i++)
    Wt[(size_t)(n0 + ty + 8*i) * E_ + k0 + tx] = __float2bfloat16(tile[tx][ty + 8*i]);
}

// ---------------- GEMM: C[M=4096][N] = A[M][K] * Bt[N][K]^T ----------------
// mode 2: N=1024, write f32 + bias to row-major [M][E]  (final output)
// mode 3: N=3072 fused QKV. cols [0,1024)->Q bf16 [BH][T][D] *scale,
//         [1024,2048)->K bf16 [BH][T][D], [2048,3072)->V bf16 [BH][D][T].
__global__ __launch_bounds__(256) void gemm_bt_kernel(
    const bf16* __restrict__ A, const bf16* __restrict__ Bt,
    void* __restrict__ out, const float* __restrict__ bias,
    const int mode, const float scale)
{
  constexpr int K = E_;
  __shared__ __align__(16) bf16 As[128*32];
  __shared__ __align__(16) bf16 Bs[128*32];
  const int tid = threadIdx.x;
  const int w = tid >> 6, l = tid & 63;
  const int lc = l & 15, lr = l >> 4;
  const int m0 = blockIdx.y * 128, n0 = blockIdx.x * 128;
  const int wr = (w >> 1) * 64, wc = (w & 1) * 64;

  f32x4 acc[4][4];
#pragma unroll
  for (int m = 0; m < 4; m++)
#pragma unroll
    for (int n = 0; n < 4; n++) acc[m][n] = (f32x4)0.0f;

  const int srow = l >> 2;            // 0..15
  const int scol = (l & 3) * 8;       // k element offset

  for (int k0 = 0; k0 < K; k0 += 32) {
#pragma unroll
    for (int p = 0; p < 2; p++) {
      const int r = (w*2 + p) * 16 + srow;
      gload_lds16(A  + (size_t)(m0 + r) * K + k0 + scol, &As[(w*2 + p) * 512]);
      gload_lds16(Bt + (size_t)(n0 + r) * K + k0 + scol, &Bs[(w*2 + p) * 512]);
    }
    __syncthreads();
    bf16x8 af[4], bfr[4];
#pragma unroll
    for (int m = 0; m < 4; m++)
      af[m] = *reinterpret_cast<const bf16x8*>(&As[(wr + m*16 + lc) * 32 + lr * 8]);
#pragma unroll
    for (int n = 0; n < 4; n++)
      bfr[n] = *reinterpret_cast<const bf16x8*>(&Bs[(wc + n*16 + lc) * 32 + lr * 8]);
#pragma unroll
    for (int m = 0; m < 4; m++)
#pragma unroll
      for (int n = 0; n < 4; n++)
        acc[m][n] = MFMA16(af[m], bfr[n], acc[m][n]);
    __syncthreads();
  }

  const int proj = blockIdx.x >> 3;   // uniform per block (mode 3)
#pragma unroll
  for (int m = 0; m < 4; m++) {
#pragma unroll
    for (int n = 0; n < 4; n++) {
#pragma unroll
      for (int j = 0; j < 4; j++) {
        const int row = m0 + wr + m*16 + lr*4 + j;   // token index
        const int col = n0 + wc + n*16 + lc;         // output feature
        if (mode == 2) {
          reinterpret_cast<float*>(out)[(size_t)row * E_ + col] = acc[m][n][j] + bias[col];
        } else {
          const int cp = col & (E_-1);
          const int b = row >> 11, t = row & (T_-1);
          const int h = cp >> 6,  d = cp & (D_-1);
          const float v = acc[m][n][j] * (proj == 0 ? scale : 1.0f);
          size_t idx;
          if (proj == 2) idx = (((size_t)(b*H_ + h)) * D_ + d) * T_ + t;      // V transposed
          else           idx = (((size_t)(b*H_ + h)) * T_ + t) * D_ + d;      // Q, K
          reinterpret_cast<bf16*>(out)[proj * PROJ_ELEMS + idx] = __float2bfloat16(v);
        }
      }
    }
  }
}

// ---------------- flash attention (causal) ----------------
// Q,K: [B*H][T][D] bf16 (Q pre-scaled by D^-0.5 * log2(e)). Vt: [B*H][D][T] bf16.
// O: [B*T][E] bf16.
// 1024 blocks, 4 waves x 16 q-rows. XCD-pinned: bid%8 selects bh-group so each
// XCD's L2 serves only 4 heads (2 MB K/V working set < 4 MB L2).
__global__ __launch_bounds__(256, 4) void attn_fwd_kernel(
    const bf16* __restrict__ Q, const bf16* __restrict__ Kt,
    const bf16* __restrict__ Vt, bf16* __restrict__ O)
{
  __shared__ __align__(16) bf16 P[4][16 * 80];   // per-wave P tile, padded stride 80
  const int tid = threadIdx.x;
  const int w = tid >> 6, l = tid & 63;
  const int lc = l & 15, lr = l >> 4;
  // XCD-pinned decode: xcd = bid&7, idx = bid>>3 (0..127)
  // bh = xcd + 8*(idx>>5)  (4 heads per XCD);  p = idx&31 work level (0 = biggest)
  const int bid = blockIdx.x;
  const int idx = bid >> 3;
  const int bh = (bid & 7) + 8 * (idx >> 5);
  const int p = idx & 31;
  const int qt = (124 - 4*p) + w;            // 0..127, each covered once per bh
  const int q0 = qt * 16;

  const bf16* Qb = Q  + (size_t)bh * T_ * D_;
  const bf16* Kb = Kt + (size_t)bh * T_ * D_;
  const bf16* Vb = Vt + (size_t)bh * D_ * T_;

  // Q fragments (held across the k loop)
  bf16x8 qf[2];
#pragma unroll
  for (int kk = 0; kk < 2; kk++)
    qf[kk] = *reinterpret_cast<const bf16x8*>(
        &Qb[(size_t)(q0 + lc) * D_ + kk*32 + lr*8]);

  f32x4 oacc[4];
  float mrow[4], lsum[4];
#pragma unroll
  for (int n = 0; n < 4; n++) oacc[n] = (f32x4)0.0f;
#pragma unroll
  for (int j = 0; j < 4; j++) { mrow[j] = -1e30f; lsum[j] = 0.0f; }

  const int nkt = (q0 >> 6) + 1;
  for (int kt = 0; kt < nkt; kt++) {
    const int kbase = kt * 64;
    // ---- S = Q K^T (K fragments transient, per n) ----
    f32x4 s[4];
#pragma unroll
    for (int n = 0; n < 4; n++) {
      bf16x8 kf0 = *reinterpret_cast<const bf16x8*>(
          &Kb[(size_t)(kbase + n*16 + lc) * D_ + lr*8]);
      bf16x8 kf1 = *reinterpret_cast<const bf16x8*>(
          &Kb[(size_t)(kbase + n*16 + lc) * D_ + 32 + lr*8]);
      s[n] = MFMA16(qf[0], kf0, (f32x4)0.0f);
      s[n] = MFMA16(qf[1], kf1, s[n]);
    }

    // ---- causal mask (log2e*scale folded into Q) ----
    if (kbase + 63 > q0) {
#pragma unroll
      for (int n = 0; n < 4; n++)
#pragma unroll
        for (int j = 0; j < 4; j++) {
          const int q = q0 + lr*4 + j;
          const int k = kbase + n*16 + lc;
          if (k > q) s[n][j] = -1e30f;
        }
    }

    // ---- row max (in-lane over n, then across the 16-lane group) ----
    float pmax[4];
#pragma unroll
    for (int j = 0; j < 4; j++)
      pmax[j] = fmaxf(fmaxf(s[0][j], s[1][j]), fmaxf(s[2][j], s[3][j]));
#pragma unroll
    for (int d = 1; d < 16; d <<= 1)
#pragma unroll
      for (int j = 0; j < 4; j++)
        pmax[j] = fmaxf(pmax[j], __shfl_xor(pmax[j], d));

    // ---- online softmax (base-2); lsum kept as per-lane partials ----
    float fsc[4];
#pragma unroll
    for (int j = 0; j < 4; j++) {
      const float mn = fmaxf(mrow[j], pmax[j]);
      fsc[j] = exp2f(mrow[j] - mn);
      mrow[j] = mn;
    }
#pragma unroll
    for (int j = 0; j < 4; j++) lsum[j] *= fsc[j];
#pragma unroll
    for (int n = 0; n < 4; n++)
#pragma unroll
      for (int j = 0; j < 4; j++) {
        const float pv = exp2f(s[n][j] - mrow[j]);
        s[n][j] = pv;
        lsum[j] += pv;
      }
#pragma unroll
    for (int n = 0; n < 4; n++)
#pragma unroll
      for (int j = 0; j < 4; j++)
        oacc[n][j] *= fsc[j];

    // ---- P -> LDS (per-wave private, no barrier needed) ----
#pragma unroll
    for (int n = 0; n < 4; n++)
#pragma unroll
      for (int j = 0; j < 4; j++)
        P[w][(lr*4 + j) * 80 + n*16 + lc] = __float2bfloat16(s[n][j]);

    // ---- O += P V (V fragments transient) ----
#pragma unroll
    for (int kk = 0; kk < 2; kk++) {
      bf16x8 pa = *reinterpret_cast<const bf16x8*>(&P[w][lc * 80 + kk*32 + lr*8]);
#pragma unroll
      for (int n = 0; n < 4; n++) {
        bf16x8 vf = *reinterpret_cast<const bf16x8*>(
            &Vb[(size_t)(n*16 + lc) * T_ + kbase + kk*32 + lr*8]);
        oacc[n] = MFMA16(pa, vf, oacc[n]);
      }
    }
  }

  // ---- epilogue: reduce lsum across the 16-lane group, then write ----
#pragma unroll
  for (int d = 1; d < 16; d <<= 1)
#pragma unroll
    for (int j = 0; j < 4; j++)
      lsum[j] += __shfl_xor(lsum[j], d);

  const int b = bh >> 4, h = bh & 15;
#pragma unroll
  for (int j = 0; j < 4; j++) {
    const float inv = 1.0f / lsum[j];
    const int row = b * T_ + q0 + lr*4 + j;
#pragma unroll
    for (int n = 0; n < 4; n++) {
      const int col = h * 64 + n*16 + lc;
      O[(size_t)row * E_ + col] = __float2bfloat16(oacc[n][j] * inv);
    }
  }
}

// ---------------- launch ----------------
extern "C" void kernel_launch(void* const* d_in, const int* in_sizes, int n_in,
                              void* d_out, int out_size, void* d_ws, size_t ws_size,
                              hipStream_t stream) {
  const float* x  = (const float*)d_in[0];
  const float* Wq = (const float*)d_in[1];
  const float* Wk = (const float*)d_in[2];
  const float* Wv = (const float*)d_in[3];
  const float* Wo = (const float*)d_in[4];
  const float* bo = (const float*)d_in[5];
  float* out = (float*)d_out;

  char* ws = (char*)d_ws;
  bf16* xb  = (bf16*)(ws);                         // 8 MB  [4096][1024]
  bf16* WqT = (bf16*)(ws + (8ull  << 20));         // 2 MB  [N][K]  (Wq|Wk|Wv contiguous)
  bf16* WkT = (bf16*)(ws + (10ull << 20));
  bf16* WvT = (bf16*)(ws + (12ull << 20));
  bf16* WoT = (bf16*)(ws + (14ull << 20));
  bf16* Qb  = (bf16*)(ws + (16ull << 20));         // 8 MB [BH][T][D]; K,V follow contiguous
  bf16* Ob  = (bf16*)(ws + (40ull << 20));         // 8 MB  [4096][1024]

  cvt_x_kernel<<<4096, 256, 0, stream>>>(x, xb);
  transpose_cvt4_kernel<<<dim3(32, 32, 4), dim3(32, 8), 0, stream>>>(
      Wq, Wk, Wv, Wo, WqT, WkT, WvT, WoT);

  // fused QKV projection: N = 3072, Bt = [WqT|WkT|WvT] contiguous
  const float qscale = 0.125f * 1.44269504f;       // D^-0.5 * log2(e)
  gemm_bt_kernel<<<dim3(24, 32), 256, 0, stream>>>(xb, WqT, Qb, nullptr, 3, qscale);

  attn_fwd_kernel<<<1024, 256, 0, stream>>>(
      Qb, Qb + PROJ_ELEMS, Qb + 2*PROJ_ELEMS, Ob);

  gemm_bt_kernel<<<dim3(8, 32), 256, 0, stream>>>(Ob, WoT, out, bo, 2, 1.0f);
}

// Round 4
// 224.296 us; speedup vs baseline: 1.3852x; 1.3852x over previous
//
#include <hip/hip_runtime.h>
#include <hip/hip_bf16.h>
#include <stdint.h>

typedef __hip_bfloat16 bf16;
typedef __attribute__((ext_vector_type(8))) short bf16x8;
typedef __attribute__((ext_vector_type(4))) float f32x4;

#define MFMA16(a,b,c) __builtin_amdgcn_mfma_f32_16x16x32_bf16((a),(b),(c),0,0,0)

#define B_ 2
#define T_ 2048
#define E_ 1024
#define H_ 16
#define D_ 64
#define M_ (B_*T_)   // 4096
#define PROJ_ELEMS (32ull * 2048ull * 64ull)   // 4.19M elems per Q/K/V tensor

__device__ __forceinline__ void gload_lds16(const bf16* g, bf16* l) {
  __builtin_amdgcn_global_load_lds(
      (const __attribute__((address_space(1))) unsigned int*)g,
      (__attribute__((address_space(3))) unsigned int*)l,
      16, 0, 0);
}

// ---------------- pre-pass: f32 -> bf16 convert ----------------
__global__ __launch_bounds__(256) void cvt_x_kernel(const float* __restrict__ in,
                                                    bf16* __restrict__ out) {
  int i = blockIdx.x * 256 + threadIdx.x;        // each thread: 4 floats
  float4 v = reinterpret_cast<const float4*>(in)[i];
  union { bf16 h[4]; unsigned long long u; } t;
  t.h[0] = __float2bfloat16(v.x);
  t.h[1] = __float2bfloat16(v.y);
  t.h[2] = __float2bfloat16(v.z);
  t.h[3] = __float2bfloat16(v.w);
  reinterpret_cast<unsigned long long*>(out)[i] = t.u;
}

// ---------------- pre-pass: 4x W [K][N] f32 -> Wt [N][K] bf16 (fused) ----------------
__global__ __launch_bounds__(256) void transpose_cvt4_kernel(
    const float* __restrict__ W0, const float* __restrict__ W1,
    const float* __restrict__ W2, const float* __restrict__ W3,
    bf16* __restrict__ T0, bf16* __restrict__ T1,
    bf16* __restrict__ T2, bf16* __restrict__ T3) {
  __shared__ float tile[32][33];
  const float* W; bf16* Wt;
  switch (blockIdx.z) {
    case 0: W = W0; Wt = T0; break;
    case 1: W = W1; Wt = T1; break;
    case 2: W = W2; Wt = T2; break;
    default: W = W3; Wt = T3; break;
  }
  const int tx = threadIdx.x, ty = threadIdx.y;  // 32 x 8
  const int n0 = blockIdx.x * 32, k0 = blockIdx.y * 32;
#pragma unroll
  for (int i = 0; i < 4; i++)
    tile[ty + 8*i][tx] = W[(size_t)(k0 + ty + 8*i) * E_ + n0 + tx];
  __syncthreads();
#pragma unroll
  for (int i = 0; i < 4; i++)
    Wt[(size_t)(n0 + ty + 8*i) * E_ + k0 + tx] = __float2bfloat16(tile[tx][ty + 8*i]);
}

// ---------------- GEMM: C[M=4096][N] = A[M][K] * Bt[N][K]^T ----------------
__global__ __launch_bounds__(256) void gemm_bt_kernel(
    const bf16* __restrict__ A, const bf16* __restrict__ Bt,
    void* __restrict__ out, const float* __restrict__ bias,
    const int mode, const float scale)
{
  constexpr int K = E_;
  __shared__ __align__(16) bf16 As[128*32];
  __shared__ __align__(16) bf16 Bs[128*32];
  const int tid = threadIdx.x;
  const int w = tid >> 6, l = tid & 63;
  const int lc = l & 15, lr = l >> 4;
  const int m0 = blockIdx.y * 128, n0 = blockIdx.x * 128;
  const int wr = (w >> 1) * 64, wc = (w & 1) * 64;

  f32x4 acc[4][4];
#pragma unroll
  for (int m = 0; m < 4; m++)
#pragma unroll
    for (int n = 0; n < 4; n++) acc[m][n] = (f32x4)0.0f;

  const int srow = l >> 2;            // 0..15
  const int scol = (l & 3) * 8;       // k element offset

  for (int k0 = 0; k0 < K; k0 += 32) {
#pragma unroll
    for (int p = 0; p < 2; p++) {
      const int r = (w*2 + p) * 16 + srow;
      gload_lds16(A  + (size_t)(m0 + r) * K + k0 + scol, &As[(w*2 + p) * 512]);
      gload_lds16(Bt + (size_t)(n0 + r) * K + k0 + scol, &Bs[(w*2 + p) * 512]);
    }
    __syncthreads();
    bf16x8 af[4], bfr[4];
#pragma unroll
    for (int m = 0; m < 4; m++)
      af[m] = *reinterpret_cast<const bf16x8*>(&As[(wr + m*16 + lc) * 32 + lr * 8]);
#pragma unroll
    for (int n = 0; n < 4; n++)
      bfr[n] = *reinterpret_cast<const bf16x8*>(&Bs[(wc + n*16 + lc) * 32 + lr * 8]);
#pragma unroll
    for (int m = 0; m < 4; m++)
#pragma unroll
      for (int n = 0; n < 4; n++)
        acc[m][n] = MFMA16(af[m], bfr[n], acc[m][n]);
    __syncthreads();
  }

  const int proj = blockIdx.x >> 3;   // uniform per block (mode 3)
#pragma unroll
  for (int m = 0; m < 4; m++) {
#pragma unroll
    for (int n = 0; n < 4; n++) {
#pragma unroll
      for (int j = 0; j < 4; j++) {
        const int row = m0 + wr + m*16 + lr*4 + j;   // token index
        const int col = n0 + wc + n*16 + lc;         // output feature
        if (mode == 2) {
          reinterpret_cast<float*>(out)[(size_t)row * E_ + col] = acc[m][n][j] + bias[col];
        } else {
          const int cp = col & (E_-1);
          const int b = row >> 11, t = row & (T_-1);
          const int h = cp >> 6,  d = cp & (D_-1);
          const float v = acc[m][n][j] * (proj == 0 ? scale : 1.0f);
          size_t idx;
          if (proj == 2) idx = (((size_t)(b*H_ + h)) * D_ + d) * T_ + t;      // V transposed
          else           idx = (((size_t)(b*H_ + h)) * T_ + t) * D_ + d;      // Q, K
          reinterpret_cast<bf16*>(out)[proj * PROJ_ELEMS + idx] = __float2bfloat16(v);
        }
      }
    }
  }
}

// ---------------- flash attention (causal), pipelined LDS-staged ----------------
// Q,K: [B*H][T][D] bf16 (Q pre-scaled by D^-0.5 * log2(e)). Vt: [B*H][D][T] bf16.
// O: [B*T][E] bf16.
// Block = 4 warps x 32 q-rows = 128 q-rows. Grid 512 = 32 bh x 16 q-blocks.
// K/V tiles (KVBLK=32) double-buffered in LDS, staged cooperatively with
// global_load_lds; XOR-swizzled (pre-swizzled source + swizzled read).
__global__ __launch_bounds__(256, 4) void attn_fwd_kernel(
    const bf16* __restrict__ Q, const bf16* __restrict__ Kt,
    const bf16* __restrict__ Vt, bf16* __restrict__ O)
{
  __shared__ __align__(16) bf16 Ks[2][32*64];   // [t][d], swizzled c16^=(t&7)
  __shared__ __align__(16) bf16 Vs[2][64*32];   // [d][t], swizzled c16^=((d>>1)&3)
  __shared__ __align__(16) bf16 P[4][32*72];    // per-warp P, stride 72

  const int tid = threadIdx.x;
  const int w = tid >> 6, l = tid & 63;
  const int lc = l & 15, lr = l >> 4;
  const int bid = blockIdx.x;
  const int bh = bid & 31;
  const int g = bid >> 5;                       // 0..15
  const int qb = (g & 1) ? (g >> 1) : (15 - (g >> 1));   // big/small interleave
  const int q0 = qb * 128 + w * 32;             // warp q base

  const bf16* Qb = Q  + (size_t)bh * T_ * D_;
  const bf16* Kb = Kt + (size_t)bh * T_ * D_;
  const bf16* Vb = Vt + (size_t)bh * D_ * T_;

  // ---- Q fragments (held in registers) ----
  bf16x8 qf[2][2];
#pragma unroll
  for (int m = 0; m < 2; m++)
#pragma unroll
    for (int kk = 0; kk < 2; kk++)
      qf[m][kk] = *reinterpret_cast<const bf16x8*>(
          &Qb[(size_t)(q0 + m*16 + lc) * D_ + kk*32 + lr*8]);

  // ---- staging lane constants ----
  // K: warp w stages rows [w*8, w*8+8); lane: row +(l>>3), col16 (l&7)^(l>>3)
  const bf16* ksrc = Kb + (size_t)((w<<3) + (l>>3)) * D_ + (((l&7) ^ (l>>3)) << 3);
  // V: warp w stages rows [w*16, w*16+16); lane: row +(l>>2), col16 (l&3)^((l>>3)&3)
  const bf16* vsrc = Vb + (size_t)((w<<4) + (l>>2)) * T_ + (((l&3) ^ ((l>>3)&3)) << 3);

  f32x4 oacc[2][4];
  float mrow[2][4], lsum[2][4];
#pragma unroll
  for (int m = 0; m < 2; m++)
#pragma unroll
    for (int n = 0; n < 4; n++) oacc[m][n] = (f32x4)0.0f;
#pragma unroll
  for (int m = 0; m < 2; m++)
#pragma unroll
    for (int j = 0; j < 4; j++) { mrow[m][j] = -1e30f; lsum[m][j] = 0.0f; }

  const int nkt = 4*qb + 4;                     // tiles of 32 for this block

  // ---- prologue: stage tile 0 into buf 0 ----
  gload_lds16(ksrc, &Ks[0][w << 9]);
  gload_lds16(vsrc, &Vs[0][w << 9]);
  __syncthreads();                              // compiler drains vmcnt before barrier

  for (int kt = 0; kt < nkt; ++kt) {
    const int kbase = kt << 5;
    const int buf = kt & 1;
    // ---- issue prefetch of next tile into other buffer ----
    if (kt + 1 < nkt) {
      gload_lds16(ksrc + (size_t)(kbase + 32) * D_, &Ks[buf^1][w << 9]);
      gload_lds16(vsrc + (kbase + 32),              &Vs[buf^1][w << 9]);
    }
    if (kbase <= q0 + 31) {                     // warp-uniform: skip fully-masked tiles
      // ---- S = Q K^T from LDS ----
      f32x4 s[2][2];
#pragma unroll
      for (int n = 0; n < 2; n++) {
        const int t = n*16 + lc;
        bf16x8 k0 = *reinterpret_cast<const bf16x8*>(
            &Ks[buf][t*64 + ((lr     ^ (lc & 7)) << 3)]);
        bf16x8 k1 = *reinterpret_cast<const bf16x8*>(
            &Ks[buf][t*64 + (((4+lr) ^ (lc & 7)) << 3)]);
        s[0][n] = MFMA16(qf[0][0], k0, (f32x4)0.0f);
        s[1][n] = MFMA16(qf[1][0], k0, (f32x4)0.0f);
        s[0][n] = MFMA16(qf[0][1], k1, s[0][n]);
        s[1][n] = MFMA16(qf[1][1], k1, s[1][n]);
      }
      // ---- causal mask ----
      if (kbase + 31 > q0) {
#pragma unroll
        for (int m = 0; m < 2; m++)
#pragma unroll
          for (int n = 0; n < 2; n++)
#pragma unroll
            for (int j = 0; j < 4; j++) {
              const int q = q0 + m*16 + lr*4 + j;
              const int k = kbase + n*16 + lc;
              if (k > q) s[m][n][j] = -1e30f;
            }
      }
      // ---- row max ----
      float pmax[2][4];
#pragma unroll
      for (int m = 0; m < 2; m++)
#pragma unroll
        for (int j = 0; j < 4; j++)
          pmax[m][j] = fmaxf(s[m][0][j], s[m][1][j]);
#pragma unroll
      for (int d = 1; d < 16; d <<= 1)
#pragma unroll
        for (int m = 0; m < 2; m++)
#pragma unroll
          for (int j = 0; j < 4; j++)
            pmax[m][j] = fmaxf(pmax[m][j], __shfl_xor(pmax[m][j], d));
      // ---- online softmax (base-2 domain) ----
      float fsc[2][4];
#pragma unroll
      for (int m = 0; m < 2; m++)
#pragma unroll
        for (int j = 0; j < 4; j++) {
          const float mn = fmaxf(mrow[m][j], pmax[m][j]);
          fsc[m][j] = exp2f(mrow[m][j] - mn);
          mrow[m][j] = mn;
          lsum[m][j] *= fsc[m][j];
        }
#pragma unroll
      for (int m = 0; m < 2; m++)
#pragma unroll
        for (int n = 0; n < 2; n++)
#pragma unroll
          for (int j = 0; j < 4; j++) {
            const float pv = exp2f(s[m][n][j] - mrow[m][j]);
            s[m][n][j] = pv;
            lsum[m][j] += pv;
          }
#pragma unroll
      for (int m = 0; m < 2; m++)
#pragma unroll
        for (int n = 0; n < 4; n++)
#pragma unroll
          for (int j = 0; j < 4; j++)
            oacc[m][n][j] *= fsc[m][j];
      // ---- P -> LDS (per-warp private) ----
#pragma unroll
      for (int m = 0; m < 2; m++)
#pragma unroll
        for (int n = 0; n < 2; n++)
#pragma unroll
          for (int j = 0; j < 4; j++)
            P[w][(m*16 + lr*4 + j)*72 + n*16 + lc] = __float2bfloat16(s[m][n][j]);
      // ---- O += P V ----
      bf16x8 pa0 = *reinterpret_cast<const bf16x8*>(&P[w][(lc)*72      + lr*8]);
      bf16x8 pa1 = *reinterpret_cast<const bf16x8*>(&P[w][(16 + lc)*72 + lr*8]);
#pragma unroll
      for (int n = 0; n < 4; n++) {
        const int dp = n*16 + lc;
        bf16x8 vf = *reinterpret_cast<const bf16x8*>(
            &Vs[buf][dp*32 + ((lr ^ ((lc>>1) & 3)) << 3)]);
        oacc[0][n] = MFMA16(pa0, vf, oacc[0][n]);
        oacc[1][n] = MFMA16(pa1, vf, oacc[1][n]);
      }
    }
    __syncthreads();                            // next buffer staged + reads done
  }

  // ---- epilogue: reduce lsum across the 16-lane group, write O ----
#pragma unroll
  for (int d = 1; d < 16; d <<= 1)
#pragma unroll
    for (int m = 0; m < 2; m++)
#pragma unroll
      for (int j = 0; j < 4; j++)
        lsum[m][j] += __shfl_xor(lsum[m][j], d);

  const int b = bh >> 4, h = bh & 15;
#pragma unroll
  for (int m = 0; m < 2; m++)
#pragma unroll
    for (int j = 0; j < 4; j++) {
      const float inv = 1.0f / lsum[m][j];
      const int row = b * T_ + q0 + m*16 + lr*4 + j;
#pragma unroll
      for (int n = 0; n < 4; n++) {
        const int col = h * 64 + n*16 + lc;
        O[(size_t)row * E_ + col] = __float2bfloat16(oacc[m][n][j] * inv);
      }
    }
}

// ---------------- launch ----------------
extern "C" void kernel_launch(void* const* d_in, const int* in_sizes, int n_in,
                              void* d_out, int out_size, void* d_ws, size_t ws_size,
                              hipStream_t stream) {
  const float* x  = (const float*)d_in[0];
  const float* Wq = (const float*)d_in[1];
  const float* Wk = (const float*)d_in[2];
  const float* Wv = (const float*)d_in[3];
  const float* Wo = (const float*)d_in[4];
  const float* bo = (const float*)d_in[5];
  float* out = (float*)d_out;

  char* ws = (char*)d_ws;
  bf16* xb  = (bf16*)(ws);                         // 8 MB  [4096][1024]
  bf16* WqT = (bf16*)(ws + (8ull  << 20));         // 2 MB  [N][K]  (Wq|Wk|Wv contiguous)
  bf16* WkT = (bf16*)(ws + (10ull << 20));
  bf16* WvT = (bf16*)(ws + (12ull << 20));
  bf16* WoT = (bf16*)(ws + (14ull << 20));
  bf16* Qb  = (bf16*)(ws + (16ull << 20));         // 8 MB [BH][T][D]; K,V follow contiguous
  bf16* Ob  = (bf16*)(ws + (40ull << 20));         // 8 MB  [4096][1024]

  cvt_x_kernel<<<4096, 256, 0, stream>>>(x, xb);
  transpose_cvt4_kernel<<<dim3(32, 32, 4), dim3(32, 8), 0, stream>>>(
      Wq, Wk, Wv, Wo, WqT, WkT, WvT, WoT);

  // fused QKV projection: N = 3072, Bt = [WqT|WkT|WvT] contiguous
  const float qscale = 0.125f * 1.44269504f;       // D^-0.5 * log2(e)
  gemm_bt_kernel<<<dim3(24, 32), 256, 0, stream>>>(xb, WqT, Qb, nullptr, 3, qscale);

  attn_fwd_kernel<<<512, 256, 0, stream>>>(
      Qb, Qb + PROJ_ELEMS, Qb + 2*PROJ_ELEMS, Ob);

  gemm_bt_kernel<<<dim3(8, 32), 256, 0, stream>>>(Ob, WoT, out, bo, 2, 1.0f);
}

// Round 5
// 153.823 us; speedup vs baseline: 2.0198x; 1.4581x over previous
//
#include <hip/hip_runtime.h>
#include <hip/hip_bf16.h>
#include <stdint.h>

typedef __hip_bfloat16 bf16;
typedef __attribute__((ext_vector_type(8))) short bf16x8;
typedef __attribute__((ext_vector_type(4))) float f32x4;
typedef __attribute__((ext_vector_type(16))) float f32x16;

#define MFMA16(a,b,c) __builtin_amdgcn_mfma_f32_16x16x32_bf16((a),(b),(c),0,0,0)
#define MFMA32(a,b,c) __builtin_amdgcn_mfma_f32_32x32x16_bf16((a),(b),(c),0,0,0)

#define B_ 2
#define T_ 2048
#define E_ 1024
#define H_ 16
#define D_ 64
#define M_ (B_*T_)   // 4096
#define PROJ_ELEMS (32ull * 2048ull * 64ull)   // 4.19M elems per Q/K/V tensor

__device__ __forceinline__ void gload_lds16(const bf16* g, bf16* l) {
  __builtin_amdgcn_global_load_lds(
      (const __attribute__((address_space(1))) unsigned int*)g,
      (__attribute__((address_space(3))) unsigned int*)l,
      16, 0, 0);
}

// ---------------- pre-pass: f32 -> bf16 convert ----------------
__global__ __launch_bounds__(256) void cvt_x_kernel(const float* __restrict__ in,
                                                    bf16* __restrict__ out) {
  int i = blockIdx.x * 256 + threadIdx.x;        // each thread: 4 floats
  float4 v = reinterpret_cast<const float4*>(in)[i];
  union { bf16 h[4]; unsigned long long u; } t;
  t.h[0] = __float2bfloat16(v.x);
  t.h[1] = __float2bfloat16(v.y);
  t.h[2] = __float2bfloat16(v.z);
  t.h[3] = __float2bfloat16(v.w);
  reinterpret_cast<unsigned long long*>(out)[i] = t.u;
}

// ---------------- pre-pass: 4x W [K][N] f32 -> Wt [N][K] bf16 (fused) ----------------
__global__ __launch_bounds__(256) void transpose_cvt4_kernel(
    const float* __restrict__ W0, const float* __restrict__ W1,
    const float* __restrict__ W2, const float* __restrict__ W3,
    bf16* __restrict__ T0, bf16* __restrict__ T1,
    bf16* __restrict__ T2, bf16* __restrict__ T3) {
  __shared__ float tile[32][33];
  const float* W; bf16* Wt;
  switch (blockIdx.z) {
    case 0: W = W0; Wt = T0; break;
    case 1: W = W1; Wt = T1; break;
    case 2: W = W2; Wt = T2; break;
    default: W = W3; Wt = T3; break;
  }
  const int tx = threadIdx.x, ty = threadIdx.y;  // 32 x 8
  const int n0 = blockIdx.x * 32, k0 = blockIdx.y * 32;
#pragma unroll
  for (int i = 0; i < 4; i++)
    tile[ty + 8*i][tx] = W[(size_t)(k0 + ty + 8*i) * E_ + n0 + tx];
  __syncthreads();
#pragma unroll
  for (int i = 0; i < 4; i++)
    Wt[(size_t)(n0 + ty + 8*i) * E_ + k0 + tx] = __float2bfloat16(tile[tx][ty + 8*i]);
}

// ---------------- GEMM: C[M=4096][N] = A[M][K] * Bt[N][K]^T ----------------
__global__ __launch_bounds__(256) void gemm_bt_kernel(
    const bf16* __restrict__ A, const bf16* __restrict__ Bt,
    void* __restrict__ out, const float* __restrict__ bias,
    const int mode, const float scale)
{
  constexpr int K = E_;
  __shared__ __align__(16) bf16 As[128*32];
  __shared__ __align__(16) bf16 Bs[128*32];
  const int tid = threadIdx.x;
  const int w = tid >> 6, l = tid & 63;
  const int lc = l & 15, lr = l >> 4;
  const int m0 = blockIdx.y * 128, n0 = blockIdx.x * 128;
  const int wr = (w >> 1) * 64, wc = (w & 1) * 64;

  f32x4 acc[4][4];
#pragma unroll
  for (int m = 0; m < 4; m++)
#pragma unroll
    for (int n = 0; n < 4; n++) acc[m][n] = (f32x4)0.0f;

  const int srow = l >> 2;            // 0..15
  const int scol = (l & 3) * 8;       // k element offset

  for (int k0 = 0; k0 < K; k0 += 32) {
#pragma unroll
    for (int p = 0; p < 2; p++) {
      const int r = (w*2 + p) * 16 + srow;
      gload_lds16(A  + (size_t)(m0 + r) * K + k0 + scol, &As[(w*2 + p) * 512]);
      gload_lds16(Bt + (size_t)(n0 + r) * K + k0 + scol, &Bs[(w*2 + p) * 512]);
    }
    __syncthreads();
    bf16x8 af[4], bfr[4];
#pragma unroll
    for (int m = 0; m < 4; m++)
      af[m] = *reinterpret_cast<const bf16x8*>(&As[(wr + m*16 + lc) * 32 + lr * 8]);
#pragma unroll
    for (int n = 0; n < 4; n++)
      bfr[n] = *reinterpret_cast<const bf16x8*>(&Bs[(wc + n*16 + lc) * 32 + lr * 8]);
#pragma unroll
    for (int m = 0; m < 4; m++)
#pragma unroll
      for (int n = 0; n < 4; n++)
        acc[m][n] = MFMA16(af[m], bfr[n], acc[m][n]);
    __syncthreads();
  }

  const int proj = blockIdx.x >> 3;   // uniform per block (mode 3)
#pragma unroll
  for (int m = 0; m < 4; m++) {
#pragma unroll
    for (int n = 0; n < 4; n++) {
#pragma unroll
      for (int j = 0; j < 4; j++) {
        const int row = m0 + wr + m*16 + lr*4 + j;   // token index
        const int col = n0 + wc + n*16 + lc;         // output feature
        if (mode == 2) {
          reinterpret_cast<float*>(out)[(size_t)row * E_ + col] = acc[m][n][j] + bias[col];
        } else {
          const int cp = col & (E_-1);
          const int b = row >> 11, t = row & (T_-1);
          const int h = cp >> 6,  d = cp & (D_-1);
          const float v = acc[m][n][j] * (proj == 0 ? scale : 1.0f);
          size_t idx;
          if (proj == 2) idx = (((size_t)(b*H_ + h)) * D_ + d) * T_ + t;      // V transposed
          else           idx = (((size_t)(b*H_ + h)) * T_ + t) * D_ + d;      // Q, K
          reinterpret_cast<bf16*>(out)[proj * PROJ_ELEMS + idx] = __float2bfloat16(v);
        }
      }
    }
  }
}

// ---------------- flash attention (causal), swapped-QK^T register-resident ----------------
// Q,K: [B*H][T][D] bf16 (Q pre-scaled by D^-0.5 * log2(e)). Vt: [B*H][D][T] bf16.
// O: [B*T][E] bf16.
// S^T = mfma32(A=K, B=Q): lane ln=l&31 owns q-column q0+ln; its 16 C-regs hold
// k-rows (r&3)+8*(r>>2)+4*hi (hi=l>>5). Softmax is per-lane scalar.
// P stays in registers: cvt_pk pairs + 4 shfl_xor(32) build PV B-frags.
// PV: O^T = mfma32(A=V^T, B=P^T). No LDS, no barriers. K/V double-buffered in regs.
// Grid: 1024 blocks x 128 thr (2 warps). Block = same bh, q-tiles {63-p, p}
// (constant total work per block). bh XCD-pinned via bid&7.
__global__ __launch_bounds__(128, 2) void attn_fwd_kernel(
    const bf16* __restrict__ Q, const bf16* __restrict__ Kt,
    const bf16* __restrict__ Vt, bf16* __restrict__ O)
{
  const int tid = threadIdx.x;
  const int w = tid >> 6, l = tid & 63;
  const int ln = l & 31;             // q-col / k-row / d-row lane index
  const int hi = l >> 5;
  const int bid = blockIdx.x;
  const int bh  = (bid & 7) * 4 + ((bid >> 3) & 3);
  const int p   = bid >> 5;          // 0..31
  const int qt  = w ? p : 63 - p;    // warp's q-tile index
  const int q0  = qt * 32;

  const bf16* Qb = Q  + (size_t)bh * T_ * D_;
  const bf16* kp = Kt + (size_t)bh * T_ * D_ + (size_t)ln * D_ + hi*8;
  const bf16* vp = Vt + (size_t)bh * D_ * T_ + (size_t)ln * T_ + hi*8;

  // Q as B-operand: qf[s] covers d = s*16 + hi*8 + 0..7 of row q0+ln
  bf16x8 qf[4];
#pragma unroll
  for (int s = 0; s < 4; s++)
    qf[s] = *reinterpret_cast<const bf16x8*>(
        &Qb[(size_t)(q0 + ln) * D_ + s*16 + hi*8]);

  f32x16 oacc0 = (f32x16)0.0f, oacc1 = (f32x16)0.0f;
  float mrow = -1e30f, psum = 0.0f;

  bf16x8 kA[4], vA[2][2], kB[4], vB[2][2];

#define LOADKV(KK, VV, KT) do {                                              \
    _Pragma("unroll")                                                        \
    for (int s_ = 0; s_ < 4; s_++)                                           \
      KK[s_] = *reinterpret_cast<const bf16x8*>(                             \
          kp + (size_t)(KT)*32*D_ + s_*16);                                  \
    _Pragma("unroll")                                                        \
    for (int a_ = 0; a_ < 2; a_++)                                           \
      _Pragma("unroll")                                                      \
      for (int s_ = 0; s_ < 2; s_++)                                         \
        VV[a_][s_] = *reinterpret_cast<const bf16x8*>(                       \
            vp + (size_t)a_*32*T_ + (KT)*32 + s_*16);                        \
  } while (0)

  union U4 { uint32_t u[4]; bf16x8 v; };
  union PK { bf16 h[2]; uint32_t u; };

#define TILE_BODY(KK, VV, KKN, VVN, KT, PRE, MASK) do {                      \
    if (PRE) { LOADKV(KKN, VVN, (KT)+1); }                                   \
    f32x16 sT = (f32x16)0.0f;                                                \
    _Pragma("unroll")                                                        \
    for (int s_ = 0; s_ < 4; s_++) sT = MFMA32(KK[s_], qf[s_], sT);          \
    if (MASK) {                                                              \
      _Pragma("unroll")                                                      \
      for (int r_ = 0; r_ < 16; r_++) {                                      \
        const int mm = (r_&3) + 8*(r_>>2) + 4*hi;                            \
        if (mm > ln) sT[r_] = -1e30f;                                        \
      }                                                                      \
    }                                                                        \
    float tmax = fmaxf(fmaxf(fmaxf(sT[0],sT[1]), fmaxf(sT[2],sT[3])),        \
                       fmaxf(fmaxf(sT[4],sT[5]), fmaxf(sT[6],sT[7])));       \
    tmax = fmaxf(tmax,                                                       \
           fmaxf(fmaxf(fmaxf(sT[8],sT[9]),  fmaxf(sT[10],sT[11])),           \
                 fmaxf(fmaxf(sT[12],sT[13]),fmaxf(sT[14],sT[15]))));         \
    tmax = fmaxf(tmax, __shfl_xor(tmax, 32));                                \
    const float mn_ = fmaxf(mrow, tmax);                                     \
    const float fsc = exp2f(mrow - mn_);                                     \
    mrow = mn_;                                                              \
    psum *= fsc;                                                             \
    _Pragma("unroll")                                                        \
    for (int r_ = 0; r_ < 16; r_++) {                                        \
      const float pe = exp2f(sT[r_] - mn_);                                  \
      sT[r_] = pe;                                                           \
      psum += pe;                                                            \
    }                                                                        \
    oacc0 *= fsc;                                                            \
    oacc1 *= fsc;                                                            \
    uint32_t u_[8];                                                          \
    _Pragma("unroll")                                                        \
    for (int i_ = 0; i_ < 8; i_++) {                                         \
      PK pk_;                                                                \
      pk_.h[0] = __float2bfloat16(sT[2*i_]);                                 \
      pk_.h[1] = __float2bfloat16(sT[2*i_+1]);                               \
      u_[i_] = pk_.u;                                                        \
    }                                                                        \
    const uint32_t x0 = __shfl_xor(hi ? u_[0] : u_[2], 32);                  \
    const uint32_t x1 = __shfl_xor(hi ? u_[1] : u_[3], 32);                  \
    const uint32_t x2 = __shfl_xor(hi ? u_[4] : u_[6], 32);                  \
    const uint32_t x3 = __shfl_xor(hi ? u_[5] : u_[7], 32);                  \
    U4 pf0, pf1;                                                             \
    pf0.u[0] = hi ? x0 : u_[0];  pf0.u[1] = hi ? x1 : u_[1];                 \
    pf0.u[2] = hi ? u_[2] : x0;  pf0.u[3] = hi ? u_[3] : x1;                 \
    pf1.u[0] = hi ? x2 : u_[4];  pf1.u[1] = hi ? x3 : u_[5];                 \
    pf1.u[2] = hi ? u_[6] : x2;  pf1.u[3] = hi ? u_[7] : x3;                 \
    oacc0 = MFMA32(VV[0][0], pf0.v, oacc0);                                  \
    oacc0 = MFMA32(VV[0][1], pf1.v, oacc0);                                  \
    oacc1 = MFMA32(VV[1][0], pf0.v, oacc1);                                  \
    oacc1 = MFMA32(VV[1][1], pf1.v, oacc1);                                  \
  } while (0)

  // prologue: tile 0 into buffer A
  LOADKV(kA, vA, 0);

  int kt = 0;
  while (kt + 2 <= qt) {
    TILE_BODY(kA, vA, kB, vB, kt,   true, false);
    TILE_BODY(kB, vB, kA, vA, kt+1, true, false);
    kt += 2;
  }
  if (kt < qt) {
    TILE_BODY(kA, vA, kB, vB, kt, true, false);
    TILE_BODY(kB, vB, kA, vA, qt, false, true);
  } else {
    TILE_BODY(kA, vA, kB, vB, qt, false, true);
  }

  // ---- epilogue ----
  psum += __shfl_xor(psum, 32);
  const float inv = 1.0f / psum;
  const int b = bh >> 4, h = bh & 15;
  const size_t rowbase = (size_t)(b * T_ + q0 + ln) * E_ + h * 64;
#pragma unroll
  for (int r = 0; r < 16; r++) {
    const int d = (r&3) + 8*(r>>2) + 4*hi;
    O[rowbase + d] = __float2bfloat16(oacc0[r] * inv);
  }
#pragma unroll
  for (int r = 0; r < 16; r++) {
    const int d = 32 + (r&3) + 8*(r>>2) + 4*hi;
    O[rowbase + d] = __float2bfloat16(oacc1[r] * inv);
  }
#undef TILE_BODY
#undef LOADKV
}

// ---------------- launch ----------------
extern "C" void kernel_launch(void* const* d_in, const int* in_sizes, int n_in,
                              void* d_out, int out_size, void* d_ws, size_t ws_size,
                              hipStream_t stream) {
  const float* x  = (const float*)d_in[0];
  const float* Wq = (const float*)d_in[1];
  const float* Wk = (const float*)d_in[2];
  const float* Wv = (const float*)d_in[3];
  const float* Wo = (const float*)d_in[4];
  const float* bo = (const float*)d_in[5];
  float* out = (float*)d_out;

  char* ws = (char*)d_ws;
  bf16* xb  = (bf16*)(ws);                         // 8 MB  [4096][1024]
  bf16* WqT = (bf16*)(ws + (8ull  << 20));         // 2 MB  [N][K]  (Wq|Wk|Wv contiguous)
  bf16* WkT = (bf16*)(ws + (10ull << 20));
  bf16* WvT = (bf16*)(ws + (12ull << 20));
  bf16* WoT = (bf16*)(ws + (14ull << 20));
  bf16* Qb  = (bf16*)(ws + (16ull << 20));         // 8 MB [BH][T][D]; K,V follow contiguous
  bf16* Ob  = (bf16*)(ws + (40ull << 20));         // 8 MB  [4096][1024]

  cvt_x_kernel<<<4096, 256, 0, stream>>>(x, xb);
  transpose_cvt4_kernel<<<dim3(32, 32, 4), dim3(32, 8), 0, stream>>>(
      Wq, Wk, Wv, Wo, WqT, WkT, WvT, WoT);

  // fused QKV projection: N = 3072, Bt = [WqT|WkT|WvT] contiguous
  const float qscale = 0.125f * 1.44269504f;       // D^-0.5 * log2(e)
  gemm_bt_kernel<<<dim3(24, 32), 256, 0, stream>>>(xb, WqT, Qb, nullptr, 3, qscale);

  attn_fwd_kernel<<<1024, 128, 0, stream>>>(
      Qb, Qb + PROJ_ELEMS, Qb + 2*PROJ_ELEMS, Ob);

  gemm_bt_kernel<<<dim3(8, 32), 256, 0, stream>>>(Ob, WoT, out, bo, 2, 1.0f);
}